// Round 10
// baseline (537.860 us; speedup 1.0000x reference)
//
#include <hip/hip_runtime.h>
#include <hip/hip_bf16.h>

#define H 64
#define PADW 88    // bf16 plane stride (shorts)
#define PADT 68    // f32 transpose-buffer stride (floats)
#define CAP 10240  // k_sortb LDS src staging capacity (40KB)
#define WSTRIDE 20480  // prepped weights per layer (shorts): u1(8192)|u2(4096)|m1(4096)|m2(4096)

typedef __attribute__((ext_vector_type(8))) short short8;
typedef __attribute__((ext_vector_type(4))) short short4v;
typedef __attribute__((ext_vector_type(4))) float floatx4;

#define MFMA(a, b, c) __builtin_amdgcn_mfma_f32_16x16x32_bf16(a, b, c, 0, 0, 0)

__device__ __forceinline__ float bf2f(short s) {
  union { unsigned int u; float f; } v;
  v.u = ((unsigned int)(unsigned short)s) << 16;
  return v.f;
}
// manual RNE (cold paths only)
__device__ __forceinline__ short f2bf(float f) {
  union { float f; unsigned int u; } v; v.f = f;
  unsigned int r = v.u + 0x7fffu + ((v.u >> 16) & 1u);  // RNE
  return (short)(r >> 16);
}
// HW packed RNE convert: dst.lo16 = bf16(a), dst.hi16 = bf16(b). 1 VALU op.
__device__ __forceinline__ unsigned int cvtpk(float a, float b) {
  unsigned int r;
  asm("v_cvt_pk_bf16_f32 %0, %1, %2" : "=v"(r) : "v"(a), "v"(b));
  return r;
}
__device__ __forceinline__ short f2bf1(float f) { return (short)cvtpk(f, f); }
__device__ __forceinline__ void split2a(float v, short& hi, short& lo) {
  unsigned int h = cvtpk(v, v);
  union { unsigned int u; float f; } t; t.u = h << 16;
  hi = (short)h;
  float res = v - t.f;
  lo = (short)cvtpk(res, res);
}
// 16 floats -> hi/lo bf16 fragments (thi[0]=av[0..7], thi[1]=av[8..15])
__device__ __forceinline__ void split16pk(const float* av, short8* thi, short8* tlo) {
  union U8 { short8 s; unsigned int u[4]; } H0, L0, H1, L1;
#pragma unroll
  for (int p = 0; p < 4; ++p) {
    float v0 = av[2 * p], v1 = av[2 * p + 1];
    unsigned int h = cvtpk(v0, v1);
    union { unsigned int u; float f; } a, b;
    a.u = h << 16; b.u = h & 0xffff0000u;
    H0.u[p] = h; L0.u[p] = cvtpk(v0 - a.f, v1 - b.f);
    float w0 = av[8 + 2 * p], w1 = av[8 + 2 * p + 1];
    unsigned int g = cvtpk(w0, w1);
    union { unsigned int u; float f; } c, d;
    c.u = g << 16; d.u = g & 0xffff0000u;
    H1.u[p] = g; L1.u[p] = cvtpk(w0 - c.f, w1 - d.f);
  }
  thi[0] = H0.s; tlo[0] = L0.s; thi[1] = H1.s; tlo[1] = L1.s;
}
__device__ __forceinline__ float ldf(const void* p, long idx, bool isf32) {
  return isf32 ? ((const float*)p)[idx] : bf2f(((const short*)p)[idx]);
}

// dtype probe
__global__ void k_probe(const short* __restrict__ x, int* __restrict__ flag) {
  __shared__ int cnt;
  if (threadIdx.x == 0) cnt = 0;
  __syncthreads();
  short s = x[threadIdx.x];
  int e = (s >> 7) & 0xFF;
  int insane = (e != 0 && (e < 100 || e > 140)) ? 1 : 0;
  atomicAdd(&cnt, insane);
  __syncthreads();
  if (threadIdx.x == 0) *flag = (cnt > 64) ? 1 : 0;  // 1 = f32 inputs
}

// h0 = relu(x @ w_in + b_in) -> hi/lo planes
__global__ void k_input2(const void* __restrict__ x, const void* __restrict__ w,
                         const void* __restrict__ b, short* __restrict__ hhi,
                         short* __restrict__ hlo, const int* __restrict__ flag, int N) {
  bool isf32 = (*flag != 0);
  int idx = blockIdx.x * 256 + threadIdx.x;
  if (idx >= N * H) return;
  int v = idx >> 6, k = idx & 63;
  float acc = ldf(b, k, isf32);
#pragma unroll
  for (int d = 0; d < 3; ++d)
    acc += ldf(x, (long)v * 3 + d, isf32) * ldf(w, d * 64 + k, isf32);
  float r = fmaxf(acc, 0.f);
  short hi, lo; split2a(r, hi, lo);
  hhi[idx] = hi; hlo[idx] = lo;
}

// ---------------- one-time weight prep: frag-major bf16 bank ----------------
// block b converts layer b: u1(K=128) | u2 | m1 | m2 (all hi-only bf16).
__global__ void k_prep(const void* __restrict__ U1, const void* __restrict__ U2,
                       const void* __restrict__ W1m, const void* __restrict__ W2m,
                       short* __restrict__ prep, const int* __restrict__ flag) {
  bool isf32 = (*flag != 0);
  int i = blockIdx.x;
  short* p = prep + (long)i * WSTRIDE;
  long oU = (long)i * 8192, oW = (long)i * 4096;
  for (int idx = threadIdx.x; idx < 8192; idx += 256) {
    int in = idx >> 6, n = idx & 63;
    int t = n >> 4, mm = n & 15, c = in >> 5, qq = (in >> 3) & 3, jj = in & 7;
    p[(((t * 4 + c) * 64) + (qq * 16 + mm)) * 8 + jj] = f2bf(ldf(U1, oU + idx, isf32));
  }
  for (int idx = threadIdx.x; idx < 4096; idx += 256) {
    int in = idx >> 6, n = idx & 63;
    int t = n >> 4, mm = n & 15, c = in >> 5, qq = (in >> 3) & 3, jj = in & 7;
    int fi = (((t * 2 + c) * 64) + (qq * 16 + mm)) * 8 + jj;
    p[8192 + fi]  = f2bf(ldf(U2, oW + idx, isf32));
    p[12288 + fi] = f2bf(ldf(W1m, oW + idx, isf32));
    p[16384 + fi] = f2bf(ldf(W2m, oW + idx, isf32));
  }
}

// ---------------- dense-write CSR build ----------------
// R10: pairs packed to 4B — (src << 8) | (dst & 255). Valid while N < 2^24.
// Bucket id dst>>8 is implied by position; in-bucket row is dst&255.
// Halves k_bin scattered-write bytes and k_sortb read bytes. Bit-identical CSR.

__global__ void k_bcount(const int* __restrict__ dstI, int* __restrict__ bcnt, int E) {
  __shared__ int cl[1024];
  int tid = threadIdx.x;
  for (int t = tid; t < 1024; t += 256) cl[t] = 0;
  __syncthreads();
  const int stride = gridDim.x * 256;
  const int nV = E >> 2;
  const int4* d4 = (const int4*)dstI;
  for (int i = blockIdx.x * 256 + tid; i < nV; i += stride) {
    int4 d = d4[i];
    atomicAdd(&cl[d.x >> 8], 1);
    atomicAdd(&cl[d.y >> 8], 1);
    atomicAdd(&cl[d.z >> 8], 1);
    atomicAdd(&cl[d.w >> 8], 1);
  }
  for (int i = (nV << 2) + blockIdx.x * 256 + tid; i < E; i += stride)
    atomicAdd(&cl[dstI[i] >> 8], 1);
  __syncthreads();
  for (int t = tid; t < 1024; t += 256)
    if (cl[t]) atomicAdd(&bcnt[t], cl[t]);
}

__global__ void k_bscan(const int* __restrict__ bcnt, int* __restrict__ bbase,
                        int* __restrict__ bcur, int* __restrict__ ctr) {
  __shared__ int s[256];
  int tid = threadIdx.x;
  if (tid < 16) ctr[tid] = 0;   // zero per-layer updm work counters
  int base = tid * 4;
  int v0 = bcnt[base], v1 = bcnt[base + 1], v2 = bcnt[base + 2], v3 = bcnt[base + 3];
  int tsum = v0 + v1 + v2 + v3;
  s[tid] = tsum;
  __syncthreads();
  for (int off = 1; off < 256; off <<= 1) {
    int x = (tid >= off) ? s[tid - off] : 0;
    __syncthreads();
    s[tid] += x;
    __syncthreads();
  }
  int excl = s[tid] - tsum;
  bbase[base] = excl;           bcur[base] = excl;
  bbase[base + 1] = excl + v0;  bcur[base + 1] = excl + v0;
  bbase[base + 2] = excl + v0 + v1;      bcur[base + 2] = excl + v0 + v1;
  bbase[base + 3] = excl + v0 + v1 + v2; bcur[base + 3] = excl + v0 + v1 + v2;
  if (tid == 255) bbase[1024] = s[255];
}

__global__ void k_bin(const int* __restrict__ srcI, const int* __restrict__ dstI,
                      int* __restrict__ bcur, int* __restrict__ pairs, int E) {
  __shared__ int cl[1024], cur[1024];
  int tid = threadIdx.x;
  int chunk = (E + gridDim.x - 1) / gridDim.x;
  int s = blockIdx.x * chunk;
  int e = min(s + chunk, E);
  for (int t = tid; t < 1024; t += 256) cl[t] = 0;
  __syncthreads();
  for (int i = s + tid; i < e; i += 256) atomicAdd(&cl[dstI[i] >> 8], 1);
  __syncthreads();
  for (int t = tid; t < 1024; t += 256)
    cur[t] = cl[t] ? atomicAdd(&bcur[t], cl[t]) : 0;
  __syncthreads();
  for (int i = s + tid; i < e; i += 256) {
    int d = dstI[i];
    int p = atomicAdd(&cur[d >> 8], 1);
    pairs[p] = (srcI[i] << 8) | (d & 255);
  }
}

__global__ __launch_bounds__(256) void k_sortb(
    const int* __restrict__ pairs, const int* __restrict__ bbase,
    int* __restrict__ rowptr, int* __restrict__ srcS, int N, int E, int B) {
  __shared__ int cnt[256], cur[256], s2[256];
  __shared__ int stage[CAP];
  int b = blockIdx.x, tid = threadIdx.x;
  int lo = b << 8;
  int W = min(256, N - lo);
  int s = bbase[b], e = bbase[b + 1];
  cnt[tid] = 0;
  __syncthreads();
  for (int i = s + tid; i < e; i += 256)
    atomicAdd(&cnt[pairs[i] & 255], 1);
  __syncthreads();
  int v = (tid < W) ? cnt[tid] : 0;
  s2[tid] = v;
  __syncthreads();
  for (int off = 1; off < 256; off <<= 1) {
    int x = (tid >= off) ? s2[tid - off] : 0;
    __syncthreads();
    s2[tid] += x;
    __syncthreads();
  }
  int excl = s2[tid] - v;
  if (tid < W) {
    rowptr[lo + tid] = s + excl;
    cur[tid] = excl;
  }
  if (b == B - 1 && tid == 0) rowptr[N] = E;
  __syncthreads();
  for (int i = s + tid; i < e; i += 256) {
    int pr = pairs[i];
    int p = atomicAdd(&cur[pr & 255], 1);
    if (p < CAP) stage[p] = pr >> 8;
    else srcS[s + p] = pr >> 8;
  }
  __syncthreads();
  int Sb = e - s;
  int lim = Sb < CAP ? Sb : CAP;
  for (int i = tid; i < lim; i += 256) srcS[s + i] = stage[i];
}

// ---------------- dense per-node message MLP (layer 0 only) ----------------
__global__ __launch_bounds__(256) void k_mlp(
    const short* __restrict__ hhi, const short* __restrict__ hlo,
    const void* __restrict__ W1, const void* __restrict__ B1,
    const void* __restrict__ W2, long oW, long oB,
    short* __restrict__ M, const int* __restrict__ flag, int N) {
  __shared__ short w1hi[64 * PADW], w1lo[64 * PADW];
  __shared__ short w2hi[64 * PADW], w2lo[64 * PADW];
  __shared__ float b1s[64];
  __shared__ float tbuf[4][16 * PADT];

  bool isf32 = (*flag != 0);
  int tid = threadIdx.x;
  for (int idx = tid; idx < 4096; idx += 256) {
    int j = idx >> 6, k = idx & 63;
    short hi, lo;
    split2a(ldf(W1, oW + idx, isf32), hi, lo);
    w1hi[k * PADW + j] = hi; w1lo[k * PADW + j] = lo;
    split2a(ldf(W2, oW + idx, isf32), hi, lo);
    w2hi[k * PADW + j] = hi; w2lo[k * PADW + j] = lo;
  }
  if (tid < 64) b1s[tid] = ldf(B1, oB + tid, isf32);
  __syncthreads();

  const int wave = tid >> 6, lane = tid & 63;
  const int m = lane & 15, quad = lane >> 4;
  float* tb = tbuf[wave];

  for (int nb = blockIdx.x * 64; nb < N; nb += gridDim.x * 64) {
    const int nBase = nb + wave * 16;
    int node = nBase + m;
    int nc = node < N ? node : N - 1;

    short8 fhi[2], flo[2];
    fhi[0] = *(const short8*)(hhi + (long)nc * H + quad * 8);
    fhi[1] = *(const short8*)(hhi + (long)nc * H + 32 + quad * 8);
    flo[0] = *(const short8*)(hlo + (long)nc * H + quad * 8);
    flo[1] = *(const short8*)(hlo + (long)nc * H + 32 + quad * 8);

    floatx4 acc[4];
#pragma unroll
    for (int t = 0; t < 4; ++t) acc[t] = (floatx4){0.f, 0.f, 0.f, 0.f};
#pragma unroll
    for (int t = 0; t < 4; ++t) {
      const short* whi = &w1hi[(t * 16 + m) * PADW + quad * 8];
      const short* wlo = &w1lo[(t * 16 + m) * PADW + quad * 8];
      acc[t] = MFMA(fhi[0], *(const short8*)(whi), acc[t]);
      acc[t] = MFMA(fhi[1], *(const short8*)(whi + 32), acc[t]);
      acc[t] = MFMA(flo[0], *(const short8*)(whi), acc[t]);
      acc[t] = MFMA(flo[1], *(const short8*)(whi + 32), acc[t]);
      acc[t] = MFMA(fhi[0], *(const short8*)(wlo), acc[t]);
      acc[t] = MFMA(fhi[1], *(const short8*)(wlo + 32), acc[t]);
    }

#pragma unroll
    for (int t = 0; t < 4; ++t) {
      int col = t * 16 + m;
      float bb = b1s[col];
#pragma unroll
      for (int r = 0; r < 4; ++r)
        tb[(quad * 4 + r) * PADT + col] = fmaxf(acc[t][r] + bb, 0.f);
    }

    float av[16];
    *(floatx4*)(av + 0)  = *(const floatx4*)(&tb[m * PADT + quad * 8]);
    *(floatx4*)(av + 4)  = *(const floatx4*)(&tb[m * PADT + quad * 8 + 4]);
    *(floatx4*)(av + 8)  = *(const floatx4*)(&tb[m * PADT + 32 + quad * 8]);
    *(floatx4*)(av + 12) = *(const floatx4*)(&tb[m * PADT + 32 + quad * 8 + 4]);
    short8 thi[2], tlo[2];
    split16pk(av, thi, tlo);

    floatx4 mac[4];
#pragma unroll
    for (int t = 0; t < 4; ++t) mac[t] = (floatx4){0.f, 0.f, 0.f, 0.f};
#pragma unroll
    for (int t = 0; t < 4; ++t) {
      const short* whi = &w2hi[(t * 16 + m) * PADW + quad * 8];
      const short* wlo = &w2lo[(t * 16 + m) * PADW + quad * 8];
      mac[t] = MFMA(thi[0], *(const short8*)(whi), mac[t]);
      mac[t] = MFMA(thi[1], *(const short8*)(whi + 32), mac[t]);
      mac[t] = MFMA(tlo[0], *(const short8*)(whi), mac[t]);
      mac[t] = MFMA(tlo[1], *(const short8*)(whi + 32), mac[t]);
      mac[t] = MFMA(thi[0], *(const short8*)(wlo), mac[t]);
      mac[t] = MFMA(thi[1], *(const short8*)(wlo + 32), mac[t]);
    }

#pragma unroll
    for (int t = 0; t < 4; ++t) {
      int col = t * 16 + m;
#pragma unroll
      for (int r = 0; r < 4; ++r) {
        int nrow = nBase + quad * 4 + r;
        if (nrow < N) M[(long)nrow * H + col] = f2bf1(mac[t][r]);
      }
    }
  }
}

// ---------------- gather-sum: agg[d] = sum_seg M[src] + deg*b2 ----------------
// (R7 proven body) 8 lanes x short8 (16B) per row; full batches unpredicated;
// tail masked. Accumulation order fixed -> bit-identical.
__global__ __launch_bounds__(256) void k_gather(
    const short* __restrict__ M, const int* __restrict__ rowptr,
    const int* __restrict__ srcS, const void* __restrict__ B2, long oB,
    short* __restrict__ agg, const int* __restrict__ flag, int N, int totWaves) {
  __shared__ float b2s[64];
  bool isf32 = (*flag != 0);
  if (threadIdx.x < 64) b2s[threadIdx.x] = ldf(B2, oB + threadIdx.x, isf32);
  __syncthreads();
  const int wave = threadIdx.x >> 6, lane = threadIdx.x & 63;
  const int g = lane >> 3, l = lane & 7;
  float b2v[8];
#pragma unroll
  for (int j = 0; j < 8; ++j) b2v[j] = b2s[l * 8 + j];

  const int gw = blockIdx.x * 4 + wave;
  const int nTask = (N + 7) >> 3;
  for (int task = gw; task < nTask; task += totWaves) {
    int n = task * 8 + g;
    bool valid = n < N;
    int nc = valid ? n : N - 1;
    int rs = rowptr[nc], re = rowptr[nc + 1];
    if (!valid) { rs = 0; re = 0; }
    float a[8];
#pragma unroll
    for (int j = 0; j < 8; ++j) a[j] = 0.f;
    int fullEnd = rs + ((re - rs) & ~7);
    int e = rs;
    for (; e < fullEnd; e += 8) {
      int sv[8];
#pragma unroll
      for (int u = 0; u < 8; ++u) sv[u] = srcS[e + u];
      short8 rr[8];
#pragma unroll
      for (int u = 0; u < 8; ++u)
        rr[u] = *(const short8*)(M + (long)sv[u] * H + l * 8);
#pragma unroll
      for (int u = 0; u < 8; ++u) {
#pragma unroll
        for (int j = 0; j < 8; ++j) a[j] += bf2f(rr[u][j]);
      }
    }
    if (e < re) {
      short8 rr[8];
#pragma unroll
      for (int u = 0; u < 8; ++u) {
        if (e + u < re)
          rr[u] = *(const short8*)(M + (long)srcS[e + u] * H + l * 8);
      }
#pragma unroll
      for (int u = 0; u < 8; ++u) {
        if (e + u < re) {
#pragma unroll
          for (int j = 0; j < 8; ++j) a[j] += bf2f(rr[u][j]);
        }
      }
    }
    if (valid) {
      float dv = (float)(re - rs);
      union { short8 s; unsigned int u[4]; } o;
#pragma unroll
      for (int p = 0; p < 4; ++p)
        o.u[p] = cvtpk(a[2 * p] + dv * b2v[2 * p], a[2 * p + 1] + dv * b2v[2 * p + 1]);
      *(short8*)(agg + (long)n * H + l * 8) = o.s;
    }
  }
}

// ---------------- persistent fused update + next-layer message MLP ----------------
// 512-thread / 8-wave blocks, vectorized register epilogue (R7, proven).
// R10: dynamic work-stealing — UB=512 (2 blocks/CU everywhere) pull 128-node
// tiles from an atomic counter. Fixes the UB=391 static imbalance (135 CUs ran
// 4 tiles while 121 ran 2). Tiles independent -> bit-identical.
__global__ __launch_bounds__(512, 4) void k_updm(
    short* __restrict__ hhi, short* __restrict__ hlo, const short* __restrict__ agg,
    const short* __restrict__ pw, const short* __restrict__ pwn,
    const void* __restrict__ UB1, const void* __restrict__ UB2,
    const void* __restrict__ G, const void* __restrict__ Bb,
    const void* __restrict__ Mm, const void* __restrict__ Vv,
    const void* __restrict__ B1m,
    long oB, long oBn,
    short* __restrict__ Mout, int* __restrict__ ctr,
    const int* __restrict__ flag, int N, int doMsg) {
  __shared__ short u1f[8192];
  __shared__ short u2f[4096];
  __shared__ short m1f[4096];
  __shared__ float b1s[64], b2s[64], scl[64], sft[64], mb1[64];
  __shared__ float tbuf[8][16 * PADT];
  __shared__ int s_t;

  bool isf32 = (*flag != 0);
  int tid = threadIdx.x;
  const int wave = tid >> 6, lane = tid & 63;
  const int m = lane & 15, quad = lane >> 4;

  // staging: pure vector copies from the prepped bank
  for (int c = tid; c < 1024; c += 512)
    ((short8*)u1f)[c] = ((const short8*)pw)[c];
  for (int c = tid; c < 512; c += 512) {
    ((short8*)u2f)[c] = ((const short8*)(pw + 8192))[c];
    ((short8*)m1f)[c] = ((const short8*)(pwn + 12288))[c];
  }
  // m2: direct global->register fragment loads (coalesced 16B/lane)
  short8 m2r[4][2];
#pragma unroll
  for (int t = 0; t < 4; ++t)
#pragma unroll
    for (int c = 0; c < 2; ++c)
      m2r[t][c] = *(const short8*)&pwn[16384 + (((t * 2 + c) * 64) + lane) * 8];
  if (tid < 64) {
    b1s[tid] = ldf(UB1, oB + tid, isf32);
    b2s[tid] = ldf(UB2, oB + tid, isf32);
    float s = ldf(G, oB + tid, isf32) * rsqrtf(ldf(Vv, oB + tid, isf32) + 1e-5f);
    scl[tid] = s;
    sft[tid] = ldf(Bb, oB + tid, isf32) - ldf(Mm, oB + tid, isf32) * s;
    mb1[tid] = ldf(B1m, oBn + tid, isf32);
  }

  float* tb = tbuf[wave];

  auto processT = [&](int nb) {
    const int nBase = nb + wave * 16;
    int node = nBase + m;
    int nc = node < N ? node : N - 1;

    short8 fhi[4], flo[2];
    fhi[0] = *(const short8*)(hhi + (long)nc * H + quad * 8);
    fhi[1] = *(const short8*)(hhi + (long)nc * H + 32 + quad * 8);
    flo[0] = *(const short8*)(hlo + (long)nc * H + quad * 8);
    flo[1] = *(const short8*)(hlo + (long)nc * H + 32 + quad * 8);
    fhi[2] = *(const short8*)(agg + (long)nc * H + quad * 8);
    fhi[3] = *(const short8*)(agg + (long)nc * H + 32 + quad * 8);

    floatx4 acc[4];
#pragma unroll
    for (int t = 0; t < 4; ++t) acc[t] = (floatx4){0.f, 0.f, 0.f, 0.f};
#pragma unroll
    for (int t = 0; t < 4; ++t) {
#pragma unroll
      for (int c = 0; c < 4; ++c) {
        const short8 w = *(const short8*)&u1f[(((t * 4 + c) * 64) + lane) * 8];
        acc[t] = MFMA(fhi[c], w, acc[t]);
        if (c < 2) acc[t] = MFMA(flo[c], w, acc[t]);
      }
    }

#pragma unroll
    for (int t = 0; t < 4; ++t) {
      int col = t * 16 + m;
      float bb = b1s[col];
#pragma unroll
      for (int r = 0; r < 4; ++r)
        tb[(quad * 4 + r) * PADT + col] = fmaxf(acc[t][r] + bb, 0.f);
    }
    float av[16];
    *(floatx4*)(av + 0)  = *(const floatx4*)(&tb[m * PADT + quad * 8]);
    *(floatx4*)(av + 4)  = *(const floatx4*)(&tb[m * PADT + quad * 8 + 4]);
    *(floatx4*)(av + 8)  = *(const floatx4*)(&tb[m * PADT + 32 + quad * 8]);
    *(floatx4*)(av + 12) = *(const floatx4*)(&tb[m * PADT + 32 + quad * 8 + 4]);
    short8 thi[2], tlo[2];
    split16pk(av, thi, tlo);

    floatx4 mac[4];
#pragma unroll
    for (int t = 0; t < 4; ++t) mac[t] = (floatx4){0.f, 0.f, 0.f, 0.f};
#pragma unroll
    for (int t = 0; t < 4; ++t) {
#pragma unroll
      for (int c = 0; c < 2; ++c) {
        const short8 w = *(const short8*)&u2f[(((t * 2 + c) * 64) + lane) * 8];
        mac[t] = MFMA(thi[c], w, mac[t]);
        mac[t] = MFMA(tlo[c], w, mac[t]);
      }
    }

    // BN affine -> tbuf; residual in registers after transpose
#pragma unroll
    for (int t = 0; t < 4; ++t) {
      int col = t * 16 + m;
      float bb = b2s[col], ss = scl[col], ff = sft[col];
#pragma unroll
      for (int r = 0; r < 4; ++r)
        tb[(quad * 4 + r) * PADT + col] = (mac[t][r] + bb) * ss + ff;
    }
    *(floatx4*)(av + 0)  = *(const floatx4*)(&tb[m * PADT + quad * 8]);
    *(floatx4*)(av + 4)  = *(const floatx4*)(&tb[m * PADT + quad * 8 + 4]);
    *(floatx4*)(av + 8)  = *(const floatx4*)(&tb[m * PADT + 32 + quad * 8]);
    *(floatx4*)(av + 12) = *(const floatx4*)(&tb[m * PADT + 32 + quad * 8 + 4]);
    float hn[16];
#pragma unroll
    for (int j = 0; j < 8; ++j) {
      hn[j]     = fmaxf(av[j]     + bf2f(fhi[0][j]) + bf2f(flo[0][j]), 0.f);
      hn[8 + j] = fmaxf(av[8 + j] + bf2f(fhi[1][j]) + bf2f(flo[1][j]), 0.f);
    }
    split16pk(hn, thi, tlo);
    if (node < N) {
      long base = (long)node * H;
      *(short8*)(hhi + base + quad * 8)      = thi[0];
      *(short8*)(hhi + base + 32 + quad * 8) = thi[1];
      *(short8*)(hlo + base + quad * 8)      = tlo[0];
      *(short8*)(hlo + base + 32 + quad * 8) = tlo[1];
    }

    if (doMsg) {
      // m1 MFMA directly on the packed hn fragments (no tbuf round-trip)
#pragma unroll
      for (int t = 0; t < 4; ++t) acc[t] = (floatx4){0.f, 0.f, 0.f, 0.f};
#pragma unroll
      for (int t = 0; t < 4; ++t) {
#pragma unroll
        for (int c = 0; c < 2; ++c) {
          const short8 w = *(const short8*)&m1f[(((t * 2 + c) * 64) + lane) * 8];
          acc[t] = MFMA(thi[c], w, acc[t]);
          acc[t] = MFMA(tlo[c], w, acc[t]);
        }
      }

#pragma unroll
      for (int t = 0; t < 4; ++t) {
        int col = t * 16 + m;
        float bb = mb1[col];
#pragma unroll
        for (int r = 0; r < 4; ++r)
          tb[(quad * 4 + r) * PADT + col] = fmaxf(acc[t][r] + bb, 0.f);
      }
      *(floatx4*)(av + 0)  = *(const floatx4*)(&tb[m * PADT + quad * 8]);
      *(floatx4*)(av + 4)  = *(const floatx4*)(&tb[m * PADT + quad * 8 + 4]);
      *(floatx4*)(av + 8)  = *(const floatx4*)(&tb[m * PADT + 32 + quad * 8]);
      *(floatx4*)(av + 12) = *(const floatx4*)(&tb[m * PADT + 32 + quad * 8 + 4]);
      split16pk(av, thi, tlo);

#pragma unroll
      for (int t = 0; t < 4; ++t) mac[t] = (floatx4){0.f, 0.f, 0.f, 0.f};
#pragma unroll
      for (int t = 0; t < 4; ++t) {
#pragma unroll
        for (int c = 0; c < 2; ++c) {
          mac[t] = MFMA(thi[c], m2r[t][c], mac[t]);
          mac[t] = MFMA(tlo[c], m2r[t][c], mac[t]);
        }
      }

      // Mout via tbuf transpose -> 2x16B row stores
#pragma unroll
      for (int t = 0; t < 4; ++t) {
        int col = t * 16 + m;
#pragma unroll
        for (int r = 0; r < 4; ++r)
          tb[(quad * 4 + r) * PADT + col] = mac[t][r];
      }
      *(floatx4*)(av + 0)  = *(const floatx4*)(&tb[m * PADT + quad * 8]);
      *(floatx4*)(av + 4)  = *(const floatx4*)(&tb[m * PADT + quad * 8 + 4]);
      *(floatx4*)(av + 8)  = *(const floatx4*)(&tb[m * PADT + 32 + quad * 8]);
      *(floatx4*)(av + 12) = *(const floatx4*)(&tb[m * PADT + 32 + quad * 8 + 4]);
      if (node < N) {
        union { short8 s; unsigned int u[4]; } M0, M1;
#pragma unroll
        for (int p = 0; p < 4; ++p) {
          M0.u[p] = cvtpk(av[2 * p], av[2 * p + 1]);
          M1.u[p] = cvtpk(av[8 + 2 * p], av[8 + 2 * p + 1]);
        }
        long base = (long)node * H;
        *(short8*)(Mout + base + quad * 8)      = M0.s;
        *(short8*)(Mout + base + 32 + quad * 8) = M1.s;
      }
    }
  };

  const int nTiles = (N + 127) >> 7;
  for (;;) {
    __syncthreads();              // staging done / previous s_t readers done
    if (tid == 0) s_t = atomicAdd(ctr, 1);
    __syncthreads();
    int t = s_t;
    if (t >= nTiles) break;
    processT(t << 7);
  }
}

// readout from hi/lo planes
__global__ __launch_bounds__(256) void k_out2(
    const short* __restrict__ hhi, const short* __restrict__ hlo,
    const void* __restrict__ W1, const void* __restrict__ B1,
    const void* __restrict__ W2, const void* __restrict__ B2,
    void* __restrict__ out, const int* __restrict__ flag, int NQ) {
  __shared__ float w1s[64 * 32];
  __shared__ float b1sh[32], w2s[32];
  bool isf32 = (*flag != 0);
  int tid = threadIdx.x;
  for (int idx = tid; idx < 2048; idx += 256) w1s[idx] = ldf(W1, idx, isf32);
  if (tid < 32) { b1sh[tid] = ldf(B1, tid, isf32); w2s[tid] = ldf(W2, tid, isf32); }
  __syncthreads();
  int v = blockIdx.x * 256 + tid;
  if (v >= NQ) return;
  float hr[64];
#pragma unroll
  for (int j = 0; j < 64; ++j)
    hr[j] = bf2f(hhi[(long)v * H + j]) + bf2f(hlo[(long)v * H + j]);
  float accum = ldf(B2, 0, isf32);
#pragma unroll 4
  for (int k = 0; k < 32; ++k) {
    float t = b1sh[k];
#pragma unroll
    for (int j = 0; j < 64; ++j) t += hr[j] * w1s[j * 32 + k];
    accum += fmaxf(t, 0.f) * w2s[k];
  }
  if (isf32) ((float*)out)[v] = accum;
  else ((short*)out)[v] = f2bf1(accum);
}

extern "C" void kernel_launch(void* const* d_in, const int* in_sizes, int n_in,
                              void* d_out, int out_size, void* d_ws, size_t ws_size,
                              hipStream_t stream) {
  const void* x      = d_in[0];
  const int*  ei     = (const int*)d_in[1];
  const void* w_in   = d_in[3];
  const void* b_in   = d_in[4];
  const void* msg_w1 = d_in[5];
  const void* msg_b1 = d_in[6];
  const void* msg_w2 = d_in[7];
  const void* msg_b2 = d_in[8];
  const void* upd_w1 = d_in[9];
  const void* upd_b1 = d_in[10];
  const void* upd_w2 = d_in[11];
  const void* upd_b2 = d_in[12];
  const void* bn_g   = d_in[13];
  const void* bn_b   = d_in[14];
  const void* bn_m   = d_in[15];
  const void* bn_v   = d_in[16];
  const void* out_w1 = d_in[17];
  const void* out_b1 = d_in[18];
  const void* out_w2 = d_in[19];
  const void* out_b2 = d_in[20];

  const int N = in_sizes[0] / 3;
  const int E = in_sizes[1] / 2;
  const int L = in_sizes[5] / (H * H);
  const int* srcI = ei;
  const int* dstI = ei + E;
  const int B = (N + 255) >> 8;

  // workspace layout (256B-aligned slots)
  size_t off = 0;
  auto alloc = [&](size_t bytes) { size_t o = off; off += (bytes + 255) & ~(size_t)255; return o; };
  size_t mSize = (size_t)N * H * sizeof(short);
  size_t pSize = (size_t)E * sizeof(int);   // packed 4B pairs
  size_t o_flag   = alloc(256);
  size_t o_bcnt   = alloc(1024 * sizeof(int));
  size_t o_bbase  = alloc(1025 * sizeof(int));
  size_t o_bcur   = alloc(1024 * sizeof(int));
  size_t o_ctr    = alloc(16 * sizeof(int));
  size_t o_prep   = alloc((size_t)L * WSTRIDE * sizeof(short));
  size_t o_hhi    = alloc((size_t)N * H * sizeof(short));
  size_t o_hlo    = alloc((size_t)N * H * sizeof(short));
  size_t o_agg    = alloc((size_t)N * H * sizeof(short));
  size_t o_M      = alloc(mSize > pSize ? mSize : pSize);  // M overlays pairs
  size_t o_rowptr = alloc((size_t)(N + 1) * sizeof(int));
  size_t o_srcS   = alloc((size_t)E * sizeof(int));

  char* ws = (char*)d_ws;
  int*   flag   = (int*)(ws + o_flag);
  int*   bcnt   = (int*)(ws + o_bcnt);
  int*   bbase  = (int*)(ws + o_bbase);
  int*   bcur   = (int*)(ws + o_bcur);
  int*   ctr    = (int*)(ws + o_ctr);
  short* prep   = (short*)(ws + o_prep);
  short* hhi    = (short*)(ws + o_hhi);
  short* hlo    = (short*)(ws + o_hlo);
  short* aggS   = (short*)(ws + o_agg);
  short* Mbuf   = (short*)(ws + o_M);
  int*   pairs  = (int*)(ws + o_M);
  int*   rowptr = (int*)(ws + o_rowptr);
  int*   srcS   = (int*)(ws + o_srcS);

  k_probe<<<1, 256, 0, stream>>>((const short*)x, flag);
  k_prep<<<L, 256, 0, stream>>>(upd_w1, upd_w2, msg_w1, msg_w2, prep, flag);
  k_input2<<<(N * H + 255) / 256, 256, 0, stream>>>(x, w_in, b_in, hhi, hlo, flag, N);

  // dense-write CSR build (packed 4B pairs)
  hipMemsetAsync(bcnt, 0, 1024 * sizeof(int), stream);
  k_bcount<<<256, 256, 0, stream>>>(dstI, bcnt, E);
  k_bscan<<<1, 256, 0, stream>>>(bcnt, bbase, bcur, ctr);
  k_bin<<<256, 256, 0, stream>>>(srcI, dstI, bcur, pairs, E);
  k_sortb<<<B, 256, 0, stream>>>(pairs, bbase, rowptr, srcS, N, E, B);

  // M_0 (full-precision standalone MLP, persistent) — after pairs is dead
  k_mlp<<<768, 256, 0, stream>>>(hhi, hlo,
      msg_w1, msg_b1, msg_w2, 0, 0, Mbuf, flag, N);

  const int nTask = (N + 7) >> 3;
  const int GB = (nTask + 7) / 8;   // 2 tasks per wave, balanced
  const int UB = 512;               // 2 blocks/CU everywhere; dynamic tile pull
  for (int i = 0; i < L; ++i) {
    long oB = (long)i * H;
    int doMsg = (i + 1 < L) ? 1 : 0;
    int iN = doMsg ? i + 1 : i;  // clamped (m1/m2 unused when !doMsg)
    long oBn = doMsg ? (long)(i + 1) * H : 0;
    k_gather<<<GB, 256, 0, stream>>>(Mbuf, rowptr, srcS,
        msg_b2, oB, aggS, flag, N, GB * 4);
    k_updm<<<UB, 512, 0, stream>>>(hhi, hlo, aggS,
        prep + (size_t)i * WSTRIDE, prep + (size_t)iN * WSTRIDE,
        upd_b1, upd_b2, bn_g, bn_b, bn_m, bn_v, msg_b1,
        oB, oBn, Mbuf, ctr + i, flag, N, doMsg);
  }
  k_out2<<<(out_size + 255) / 256, 256, 0, stream>>>(hhi, hlo,
      out_w1, out_b1, out_w2, out_b2, d_out, flag, out_size);
}

// Round 11
// 502.990 us; speedup vs baseline: 1.0693x; 1.0693x over previous
//
#include <hip/hip_runtime.h>
#include <hip/hip_bf16.h>

#define H 64
#define PADW 88    // bf16 plane stride (shorts)
#define PADT 68    // f32 transpose-buffer stride (floats)
#define CAP 10240  // k_sortb LDS src staging capacity (40KB)
#define WSTRIDE 20480  // prepped weights per layer (shorts): u1(8192)|u2(4096)|m1(4096)|m2(4096)

typedef __attribute__((ext_vector_type(8))) short short8;
typedef __attribute__((ext_vector_type(4))) short short4v;
typedef __attribute__((ext_vector_type(4))) float floatx4;

#define MFMA(a, b, c) __builtin_amdgcn_mfma_f32_16x16x32_bf16(a, b, c, 0, 0, 0)

__device__ __forceinline__ float bf2f(short s) {
  union { unsigned int u; float f; } v;
  v.u = ((unsigned int)(unsigned short)s) << 16;
  return v.f;
}
// manual RNE (cold paths only)
__device__ __forceinline__ short f2bf(float f) {
  union { float f; unsigned int u; } v; v.f = f;
  unsigned int r = v.u + 0x7fffu + ((v.u >> 16) & 1u);  // RNE
  return (short)(r >> 16);
}
// HW packed RNE convert: dst.lo16 = bf16(a), dst.hi16 = bf16(b). 1 VALU op.
__device__ __forceinline__ unsigned int cvtpk(float a, float b) {
  unsigned int r;
  asm("v_cvt_pk_bf16_f32 %0, %1, %2" : "=v"(r) : "v"(a), "v"(b));
  return r;
}
__device__ __forceinline__ short f2bf1(float f) { return (short)cvtpk(f, f); }
__device__ __forceinline__ void split2a(float v, short& hi, short& lo) {
  unsigned int h = cvtpk(v, v);
  union { unsigned int u; float f; } t; t.u = h << 16;
  hi = (short)h;
  float res = v - t.f;
  lo = (short)cvtpk(res, res);
}
// 16 floats -> hi/lo bf16 fragments (thi[0]=av[0..7], thi[1]=av[8..15])
__device__ __forceinline__ void split16pk(const float* av, short8* thi, short8* tlo) {
  union U8 { short8 s; unsigned int u[4]; } H0, L0, H1, L1;
#pragma unroll
  for (int p = 0; p < 4; ++p) {
    float v0 = av[2 * p], v1 = av[2 * p + 1];
    unsigned int h = cvtpk(v0, v1);
    union { unsigned int u; float f; } a, b;
    a.u = h << 16; b.u = h & 0xffff0000u;
    H0.u[p] = h; L0.u[p] = cvtpk(v0 - a.f, v1 - b.f);
    float w0 = av[8 + 2 * p], w1 = av[8 + 2 * p + 1];
    unsigned int g = cvtpk(w0, w1);
    union { unsigned int u; float f; } c, d;
    c.u = g << 16; d.u = g & 0xffff0000u;
    H1.u[p] = g; L1.u[p] = cvtpk(w0 - c.f, w1 - d.f);
  }
  thi[0] = H0.s; tlo[0] = L0.s; thi[1] = H1.s; tlo[1] = L1.s;
}
__device__ __forceinline__ float ldf(const void* p, long idx, bool isf32) {
  return isf32 ? ((const float*)p)[idx] : bf2f(((const short*)p)[idx]);
}

// dtype probe
__global__ void k_probe(const short* __restrict__ x, int* __restrict__ flag) {
  __shared__ int cnt;
  if (threadIdx.x == 0) cnt = 0;
  __syncthreads();
  short s = x[threadIdx.x];
  int e = (s >> 7) & 0xFF;
  int insane = (e != 0 && (e < 100 || e > 140)) ? 1 : 0;
  atomicAdd(&cnt, insane);
  __syncthreads();
  if (threadIdx.x == 0) *flag = (cnt > 64) ? 1 : 0;  // 1 = f32 inputs
}

// h0 = relu(x @ w_in + b_in) -> hi/lo planes
__global__ void k_input2(const void* __restrict__ x, const void* __restrict__ w,
                         const void* __restrict__ b, short* __restrict__ hhi,
                         short* __restrict__ hlo, const int* __restrict__ flag, int N) {
  bool isf32 = (*flag != 0);
  int idx = blockIdx.x * 256 + threadIdx.x;
  if (idx >= N * H) return;
  int v = idx >> 6, k = idx & 63;
  float acc = ldf(b, k, isf32);
#pragma unroll
  for (int d = 0; d < 3; ++d)
    acc += ldf(x, (long)v * 3 + d, isf32) * ldf(w, d * 64 + k, isf32);
  float r = fmaxf(acc, 0.f);
  short hi, lo; split2a(r, hi, lo);
  hhi[idx] = hi; hlo[idx] = lo;
}

// ---------------- one-time weight prep: frag-major bf16 bank ----------------
// block b converts layer b: u1(K=128) | u2 | m1 | m2 (all hi-only bf16).
__global__ void k_prep(const void* __restrict__ U1, const void* __restrict__ U2,
                       const void* __restrict__ W1m, const void* __restrict__ W2m,
                       short* __restrict__ prep, const int* __restrict__ flag) {
  bool isf32 = (*flag != 0);
  int i = blockIdx.x;
  short* p = prep + (long)i * WSTRIDE;
  long oU = (long)i * 8192, oW = (long)i * 4096;
  for (int idx = threadIdx.x; idx < 8192; idx += 256) {
    int in = idx >> 6, n = idx & 63;
    int t = n >> 4, mm = n & 15, c = in >> 5, qq = (in >> 3) & 3, jj = in & 7;
    p[(((t * 4 + c) * 64) + (qq * 16 + mm)) * 8 + jj] = f2bf(ldf(U1, oU + idx, isf32));
  }
  for (int idx = threadIdx.x; idx < 4096; idx += 256) {
    int in = idx >> 6, n = idx & 63;
    int t = n >> 4, mm = n & 15, c = in >> 5, qq = (in >> 3) & 3, jj = in & 7;
    int fi = (((t * 2 + c) * 64) + (qq * 16 + mm)) * 8 + jj;
    p[8192 + fi]  = f2bf(ldf(U2, oW + idx, isf32));
    p[12288 + fi] = f2bf(ldf(W1m, oW + idx, isf32));
    p[16384 + fi] = f2bf(ldf(W2m, oW + idx, isf32));
  }
}

// ---------------- dense-write CSR build ----------------
// pairs packed to 4B — (src << 8) | (dst & 255); bucket id dst>>8 implied by
// position. Halves k_bin scattered-write bytes + k_sortb reads. Bit-identical.

__global__ void k_bcount(const int* __restrict__ dstI, int* __restrict__ bcnt, int E) {
  __shared__ int cl[1024];
  int tid = threadIdx.x;
  for (int t = tid; t < 1024; t += 256) cl[t] = 0;
  __syncthreads();
  const int stride = gridDim.x * 256;
  const int nV = E >> 2;
  const int4* d4 = (const int4*)dstI;
  for (int i = blockIdx.x * 256 + tid; i < nV; i += stride) {
    int4 d = d4[i];
    atomicAdd(&cl[d.x >> 8], 1);
    atomicAdd(&cl[d.y >> 8], 1);
    atomicAdd(&cl[d.z >> 8], 1);
    atomicAdd(&cl[d.w >> 8], 1);
  }
  for (int i = (nV << 2) + blockIdx.x * 256 + tid; i < E; i += stride)
    atomicAdd(&cl[dstI[i] >> 8], 1);
  __syncthreads();
  for (int t = tid; t < 1024; t += 256)
    if (cl[t]) atomicAdd(&bcnt[t], cl[t]);
}

__global__ void k_bscan(const int* __restrict__ bcnt, int* __restrict__ bbase,
                        int* __restrict__ bcur) {
  __shared__ int s[256];
  int tid = threadIdx.x;
  int base = tid * 4;
  int v0 = bcnt[base], v1 = bcnt[base + 1], v2 = bcnt[base + 2], v3 = bcnt[base + 3];
  int tsum = v0 + v1 + v2 + v3;
  s[tid] = tsum;
  __syncthreads();
  for (int off = 1; off < 256; off <<= 1) {
    int x = (tid >= off) ? s[tid - off] : 0;
    __syncthreads();
    s[tid] += x;
    __syncthreads();
  }
  int excl = s[tid] - tsum;
  bbase[base] = excl;           bcur[base] = excl;
  bbase[base + 1] = excl + v0;  bcur[base + 1] = excl + v0;
  bbase[base + 2] = excl + v0 + v1;      bcur[base + 2] = excl + v0 + v1;
  bbase[base + 3] = excl + v0 + v1 + v2; bcur[base + 3] = excl + v0 + v1 + v2;
  if (tid == 255) bbase[1024] = s[255];
}

__global__ void k_bin(const int* __restrict__ srcI, const int* __restrict__ dstI,
                      int* __restrict__ bcur, int* __restrict__ pairs, int E) {
  __shared__ int cl[1024], cur[1024];
  int tid = threadIdx.x;
  int chunk = (E + gridDim.x - 1) / gridDim.x;
  int s = blockIdx.x * chunk;
  int e = min(s + chunk, E);
  for (int t = tid; t < 1024; t += 256) cl[t] = 0;
  __syncthreads();
  for (int i = s + tid; i < e; i += 256) atomicAdd(&cl[dstI[i] >> 8], 1);
  __syncthreads();
  for (int t = tid; t < 1024; t += 256)
    cur[t] = cl[t] ? atomicAdd(&bcur[t], cl[t]) : 0;
  __syncthreads();
  for (int i = s + tid; i < e; i += 256) {
    int d = dstI[i];
    int p = atomicAdd(&cur[d >> 8], 1);
    pairs[p] = (srcI[i] << 8) | (d & 255);
  }
}

__global__ __launch_bounds__(256) void k_sortb(
    const int* __restrict__ pairs, const int* __restrict__ bbase,
    int* __restrict__ rowptr, int* __restrict__ srcS, int N, int E, int B) {
  __shared__ int cnt[256], cur[256], s2[256];
  __shared__ int stage[CAP];
  int b = blockIdx.x, tid = threadIdx.x;
  int lo = b << 8;
  int W = min(256, N - lo);
  int s = bbase[b], e = bbase[b + 1];
  cnt[tid] = 0;
  __syncthreads();
  for (int i = s + tid; i < e; i += 256)
    atomicAdd(&cnt[pairs[i] & 255], 1);
  __syncthreads();
  int v = (tid < W) ? cnt[tid] : 0;
  s2[tid] = v;
  __syncthreads();
  for (int off = 1; off < 256; off <<= 1) {
    int x = (tid >= off) ? s2[tid - off] : 0;
    __syncthreads();
    s2[tid] += x;
    __syncthreads();
  }
  int excl = s2[tid] - v;
  if (tid < W) {
    rowptr[lo + tid] = s + excl;
    cur[tid] = excl;
  }
  if (b == B - 1 && tid == 0) rowptr[N] = E;
  __syncthreads();
  for (int i = s + tid; i < e; i += 256) {
    int pr = pairs[i];
    int p = atomicAdd(&cur[pr & 255], 1);
    if (p < CAP) stage[p] = pr >> 8;
    else srcS[s + p] = pr >> 8;
  }
  __syncthreads();
  int Sb = e - s;
  int lim = Sb < CAP ? Sb : CAP;
  for (int i = tid; i < lim; i += 256) srcS[s + i] = stage[i];
}

// ---------------- dense per-node message MLP (layer 0 only) ----------------
__global__ __launch_bounds__(256) void k_mlp(
    const short* __restrict__ hhi, const short* __restrict__ hlo,
    const void* __restrict__ W1, const void* __restrict__ B1,
    const void* __restrict__ W2, long oW, long oB,
    short* __restrict__ M, const int* __restrict__ flag, int N) {
  __shared__ short w1hi[64 * PADW], w1lo[64 * PADW];
  __shared__ short w2hi[64 * PADW], w2lo[64 * PADW];
  __shared__ float b1s[64];
  __shared__ float tbuf[4][16 * PADT];

  bool isf32 = (*flag != 0);
  int tid = threadIdx.x;
  for (int idx = tid; idx < 4096; idx += 256) {
    int j = idx >> 6, k = idx & 63;
    short hi, lo;
    split2a(ldf(W1, oW + idx, isf32), hi, lo);
    w1hi[k * PADW + j] = hi; w1lo[k * PADW + j] = lo;
    split2a(ldf(W2, oW + idx, isf32), hi, lo);
    w2hi[k * PADW + j] = hi; w2lo[k * PADW + j] = lo;
  }
  if (tid < 64) b1s[tid] = ldf(B1, oB + tid, isf32);
  __syncthreads();

  const int wave = tid >> 6, lane = tid & 63;
  const int m = lane & 15, quad = lane >> 4;
  float* tb = tbuf[wave];

  for (int nb = blockIdx.x * 64; nb < N; nb += gridDim.x * 64) {
    const int nBase = nb + wave * 16;
    int node = nBase + m;
    int nc = node < N ? node : N - 1;

    short8 fhi[2], flo[2];
    fhi[0] = *(const short8*)(hhi + (long)nc * H + quad * 8);
    fhi[1] = *(const short8*)(hhi + (long)nc * H + 32 + quad * 8);
    flo[0] = *(const short8*)(hlo + (long)nc * H + quad * 8);
    flo[1] = *(const short8*)(hlo + (long)nc * H + 32 + quad * 8);

    floatx4 acc[4];
#pragma unroll
    for (int t = 0; t < 4; ++t) acc[t] = (floatx4){0.f, 0.f, 0.f, 0.f};
#pragma unroll
    for (int t = 0; t < 4; ++t) {
      const short* whi = &w1hi[(t * 16 + m) * PADW + quad * 8];
      const short* wlo = &w1lo[(t * 16 + m) * PADW + quad * 8];
      acc[t] = MFMA(fhi[0], *(const short8*)(whi), acc[t]);
      acc[t] = MFMA(fhi[1], *(const short8*)(whi + 32), acc[t]);
      acc[t] = MFMA(flo[0], *(const short8*)(whi), acc[t]);
      acc[t] = MFMA(flo[1], *(const short8*)(whi + 32), acc[t]);
      acc[t] = MFMA(fhi[0], *(const short8*)(wlo), acc[t]);
      acc[t] = MFMA(fhi[1], *(const short8*)(wlo + 32), acc[t]);
    }

#pragma unroll
    for (int t = 0; t < 4; ++t) {
      int col = t * 16 + m;
      float bb = b1s[col];
#pragma unroll
      for (int r = 0; r < 4; ++r)
        tb[(quad * 4 + r) * PADT + col] = fmaxf(acc[t][r] + bb, 0.f);
    }

    float av[16];
    *(floatx4*)(av + 0)  = *(const floatx4*)(&tb[m * PADT + quad * 8]);
    *(floatx4*)(av + 4)  = *(const floatx4*)(&tb[m * PADT + quad * 8 + 4]);
    *(floatx4*)(av + 8)  = *(const floatx4*)(&tb[m * PADT + 32 + quad * 8]);
    *(floatx4*)(av + 12) = *(const floatx4*)(&tb[m * PADT + 32 + quad * 8 + 4]);
    short8 thi[2], tlo[2];
    split16pk(av, thi, tlo);

    floatx4 mac[4];
#pragma unroll
    for (int t = 0; t < 4; ++t) mac[t] = (floatx4){0.f, 0.f, 0.f, 0.f};
#pragma unroll
    for (int t = 0; t < 4; ++t) {
      const short* whi = &w2hi[(t * 16 + m) * PADW + quad * 8];
      const short* wlo = &w2lo[(t * 16 + m) * PADW + quad * 8];
      mac[t] = MFMA(thi[0], *(const short8*)(whi), mac[t]);
      mac[t] = MFMA(thi[1], *(const short8*)(whi + 32), mac[t]);
      mac[t] = MFMA(tlo[0], *(const short8*)(whi), mac[t]);
      mac[t] = MFMA(tlo[1], *(const short8*)(whi + 32), mac[t]);
      mac[t] = MFMA(thi[0], *(const short8*)(wlo), mac[t]);
      mac[t] = MFMA(thi[1], *(const short8*)(wlo + 32), mac[t]);
    }

#pragma unroll
    for (int t = 0; t < 4; ++t) {
      int col = t * 16 + m;
#pragma unroll
      for (int r = 0; r < 4; ++r) {
        int nrow = nBase + quad * 4 + r;
        if (nrow < N) M[(long)nrow * H + col] = f2bf1(mac[t][r]);
      }
    }
  }
}

// ---------------- gather-sum: agg[d] = sum_seg M[src] + deg*b2 ----------------
// (R7 proven body) 8 lanes x short8 (16B) per row; full batches unpredicated;
// tail masked. Accumulation order fixed -> bit-identical.
__global__ __launch_bounds__(256) void k_gather(
    const short* __restrict__ M, const int* __restrict__ rowptr,
    const int* __restrict__ srcS, const void* __restrict__ B2, long oB,
    short* __restrict__ agg, const int* __restrict__ flag, int N, int totWaves) {
  __shared__ float b2s[64];
  bool isf32 = (*flag != 0);
  if (threadIdx.x < 64) b2s[threadIdx.x] = ldf(B2, oB + threadIdx.x, isf32);
  __syncthreads();
  const int wave = threadIdx.x >> 6, lane = threadIdx.x & 63;
  const int g = lane >> 3, l = lane & 7;
  float b2v[8];
#pragma unroll
  for (int j = 0; j < 8; ++j) b2v[j] = b2s[l * 8 + j];

  const int gw = blockIdx.x * 4 + wave;
  const int nTask = (N + 7) >> 3;
  for (int task = gw; task < nTask; task += totWaves) {
    int n = task * 8 + g;
    bool valid = n < N;
    int nc = valid ? n : N - 1;
    int rs = rowptr[nc], re = rowptr[nc + 1];
    if (!valid) { rs = 0; re = 0; }
    float a[8];
#pragma unroll
    for (int j = 0; j < 8; ++j) a[j] = 0.f;
    int fullEnd = rs + ((re - rs) & ~7);
    int e = rs;
    for (; e < fullEnd; e += 8) {
      int sv[8];
#pragma unroll
      for (int u = 0; u < 8; ++u) sv[u] = srcS[e + u];
      short8 rr[8];
#pragma unroll
      for (int u = 0; u < 8; ++u)
        rr[u] = *(const short8*)(M + (long)sv[u] * H + l * 8);
#pragma unroll
      for (int u = 0; u < 8; ++u) {
#pragma unroll
        for (int j = 0; j < 8; ++j) a[j] += bf2f(rr[u][j]);
      }
    }
    if (e < re) {
      short8 rr[8];
#pragma unroll
      for (int u = 0; u < 8; ++u) {
        if (e + u < re)
          rr[u] = *(const short8*)(M + (long)srcS[e + u] * H + l * 8);
      }
#pragma unroll
      for (int u = 0; u < 8; ++u) {
        if (e + u < re) {
#pragma unroll
          for (int j = 0; j < 8; ++j) a[j] += bf2f(rr[u][j]);
        }
      }
    }
    if (valid) {
      float dv = (float)(re - rs);
      union { short8 s; unsigned int u[4]; } o;
#pragma unroll
      for (int p = 0; p < 4; ++p)
        o.u[p] = cvtpk(a[2 * p] + dv * b2v[2 * p], a[2 * p + 1] + dv * b2v[2 * p + 1]);
      *(short8*)(agg + (long)n * H + l * 8) = o.s;
    }
  }
}

// ---------------- persistent fused update + next-layer message MLP ----------------
// 512-thread / 8-wave blocks, vectorized register epilogue (R7, proven @508.8).
// Static grid 391 = ceil(N/256): exactly 2 tiles per wave, no per-tile barriers.
__global__ __launch_bounds__(512, 4) void k_updm(
    short* __restrict__ hhi, short* __restrict__ hlo, const short* __restrict__ agg,
    const short* __restrict__ pw, const short* __restrict__ pwn,
    const void* __restrict__ UB1, const void* __restrict__ UB2,
    const void* __restrict__ G, const void* __restrict__ Bb,
    const void* __restrict__ Mm, const void* __restrict__ Vv,
    const void* __restrict__ B1m,
    long oB, long oBn,
    short* __restrict__ Mout, const int* __restrict__ flag, int N, int doMsg) {
  __shared__ short u1f[8192];
  __shared__ short u2f[4096];
  __shared__ short m1f[4096];
  __shared__ float b1s[64], b2s[64], scl[64], sft[64], mb1[64];
  __shared__ float tbuf[8][16 * PADT];

  bool isf32 = (*flag != 0);
  int tid = threadIdx.x;
  const int wave = tid >> 6, lane = tid & 63;
  const int m = lane & 15, quad = lane >> 4;

  // staging: pure vector copies from the prepped bank
  for (int c = tid; c < 1024; c += 512)
    ((short8*)u1f)[c] = ((const short8*)pw)[c];
  for (int c = tid; c < 512; c += 512) {
    ((short8*)u2f)[c] = ((const short8*)(pw + 8192))[c];
    ((short8*)m1f)[c] = ((const short8*)(pwn + 12288))[c];
  }
  // m2: direct global->register fragment loads (coalesced 16B/lane)
  short8 m2r[4][2];
#pragma unroll
  for (int t = 0; t < 4; ++t)
#pragma unroll
    for (int c = 0; c < 2; ++c)
      m2r[t][c] = *(const short8*)&pwn[16384 + (((t * 2 + c) * 64) + lane) * 8];
  if (tid < 64) {
    b1s[tid] = ldf(UB1, oB + tid, isf32);
    b2s[tid] = ldf(UB2, oB + tid, isf32);
    float s = ldf(G, oB + tid, isf32) * rsqrtf(ldf(Vv, oB + tid, isf32) + 1e-5f);
    scl[tid] = s;
    sft[tid] = ldf(Bb, oB + tid, isf32) - ldf(Mm, oB + tid, isf32) * s;
    mb1[tid] = ldf(B1m, oBn + tid, isf32);
  }
  __syncthreads();

  float* tb = tbuf[wave];

  for (int nb = blockIdx.x * 128; nb < N; nb += gridDim.x * 128) {
    const int nBase = nb + wave * 16;
    int node = nBase + m;
    int nc = node < N ? node : N - 1;

    short8 fhi[4], flo[2];
    fhi[0] = *(const short8*)(hhi + (long)nc * H + quad * 8);
    fhi[1] = *(const short8*)(hhi + (long)nc * H + 32 + quad * 8);
    flo[0] = *(const short8*)(hlo + (long)nc * H + quad * 8);
    flo[1] = *(const short8*)(hlo + (long)nc * H + 32 + quad * 8);
    fhi[2] = *(const short8*)(agg + (long)nc * H + quad * 8);
    fhi[3] = *(const short8*)(agg + (long)nc * H + 32 + quad * 8);

    floatx4 acc[4];
#pragma unroll
    for (int t = 0; t < 4; ++t) acc[t] = (floatx4){0.f, 0.f, 0.f, 0.f};
#pragma unroll
    for (int t = 0; t < 4; ++t) {
#pragma unroll
      for (int c = 0; c < 4; ++c) {
        const short8 w = *(const short8*)&u1f[(((t * 4 + c) * 64) + lane) * 8];
        acc[t] = MFMA(fhi[c], w, acc[t]);
        if (c < 2) acc[t] = MFMA(flo[c], w, acc[t]);
      }
    }

#pragma unroll
    for (int t = 0; t < 4; ++t) {
      int col = t * 16 + m;
      float bb = b1s[col];
#pragma unroll
      for (int r = 0; r < 4; ++r)
        tb[(quad * 4 + r) * PADT + col] = fmaxf(acc[t][r] + bb, 0.f);
    }
    float av[16];
    *(floatx4*)(av + 0)  = *(const floatx4*)(&tb[m * PADT + quad * 8]);
    *(floatx4*)(av + 4)  = *(const floatx4*)(&tb[m * PADT + quad * 8 + 4]);
    *(floatx4*)(av + 8)  = *(const floatx4*)(&tb[m * PADT + 32 + quad * 8]);
    *(floatx4*)(av + 12) = *(const floatx4*)(&tb[m * PADT + 32 + quad * 8 + 4]);
    short8 thi[2], tlo[2];
    split16pk(av, thi, tlo);

    floatx4 mac[4];
#pragma unroll
    for (int t = 0; t < 4; ++t) mac[t] = (floatx4){0.f, 0.f, 0.f, 0.f};
#pragma unroll
    for (int t = 0; t < 4; ++t) {
#pragma unroll
      for (int c = 0; c < 2; ++c) {
        const short8 w = *(const short8*)&u2f[(((t * 2 + c) * 64) + lane) * 8];
        mac[t] = MFMA(thi[c], w, mac[t]);
        mac[t] = MFMA(tlo[c], w, mac[t]);
      }
    }

    // BN affine -> tbuf; residual in registers after transpose
#pragma unroll
    for (int t = 0; t < 4; ++t) {
      int col = t * 16 + m;
      float bb = b2s[col], ss = scl[col], ff = sft[col];
#pragma unroll
      for (int r = 0; r < 4; ++r)
        tb[(quad * 4 + r) * PADT + col] = (mac[t][r] + bb) * ss + ff;
    }
    *(floatx4*)(av + 0)  = *(const floatx4*)(&tb[m * PADT + quad * 8]);
    *(floatx4*)(av + 4)  = *(const floatx4*)(&tb[m * PADT + quad * 8 + 4]);
    *(floatx4*)(av + 8)  = *(const floatx4*)(&tb[m * PADT + 32 + quad * 8]);
    *(floatx4*)(av + 12) = *(const floatx4*)(&tb[m * PADT + 32 + quad * 8 + 4]);
    // residual + relu vs in-register h (fhi/flo have the same (m,quad) layout)
    float hn[16];
#pragma unroll
    for (int j = 0; j < 8; ++j) {
      hn[j]     = fmaxf(av[j]     + bf2f(fhi[0][j]) + bf2f(flo[0][j]), 0.f);
      hn[8 + j] = fmaxf(av[8 + j] + bf2f(fhi[1][j]) + bf2f(flo[1][j]), 0.f);
    }
    split16pk(hn, thi, tlo);
    if (node < N) {
      long base = (long)node * H;
      *(short8*)(hhi + base + quad * 8)      = thi[0];
      *(short8*)(hhi + base + 32 + quad * 8) = thi[1];
      *(short8*)(hlo + base + quad * 8)      = tlo[0];
      *(short8*)(hlo + base + 32 + quad * 8) = tlo[1];
    }

    if (doMsg) {
      // m1 MFMA directly on the packed hn fragments (no tbuf round-trip)
#pragma unroll
      for (int t = 0; t < 4; ++t) acc[t] = (floatx4){0.f, 0.f, 0.f, 0.f};
#pragma unroll
      for (int t = 0; t < 4; ++t) {
#pragma unroll
        for (int c = 0; c < 2; ++c) {
          const short8 w = *(const short8*)&m1f[(((t * 2 + c) * 64) + lane) * 8];
          acc[t] = MFMA(thi[c], w, acc[t]);
          acc[t] = MFMA(tlo[c], w, acc[t]);
        }
      }

#pragma unroll
      for (int t = 0; t < 4; ++t) {
        int col = t * 16 + m;
        float bb = mb1[col];
#pragma unroll
        for (int r = 0; r < 4; ++r)
          tb[(quad * 4 + r) * PADT + col] = fmaxf(acc[t][r] + bb, 0.f);
      }
      *(floatx4*)(av + 0)  = *(const floatx4*)(&tb[m * PADT + quad * 8]);
      *(floatx4*)(av + 4)  = *(const floatx4*)(&tb[m * PADT + quad * 8 + 4]);
      *(floatx4*)(av + 8)  = *(const floatx4*)(&tb[m * PADT + 32 + quad * 8]);
      *(floatx4*)(av + 12) = *(const floatx4*)(&tb[m * PADT + 32 + quad * 8 + 4]);
      split16pk(av, thi, tlo);

#pragma unroll
      for (int t = 0; t < 4; ++t) mac[t] = (floatx4){0.f, 0.f, 0.f, 0.f};
#pragma unroll
      for (int t = 0; t < 4; ++t) {
#pragma unroll
        for (int c = 0; c < 2; ++c) {
          mac[t] = MFMA(thi[c], m2r[t][c], mac[t]);
          mac[t] = MFMA(tlo[c], m2r[t][c], mac[t]);
        }
      }

      // Mout via tbuf transpose -> 2x16B row stores
#pragma unroll
      for (int t = 0; t < 4; ++t) {
        int col = t * 16 + m;
#pragma unroll
        for (int r = 0; r < 4; ++r)
          tb[(quad * 4 + r) * PADT + col] = mac[t][r];
      }
      *(floatx4*)(av + 0)  = *(const floatx4*)(&tb[m * PADT + quad * 8]);
      *(floatx4*)(av + 4)  = *(const floatx4*)(&tb[m * PADT + quad * 8 + 4]);
      *(floatx4*)(av + 8)  = *(const floatx4*)(&tb[m * PADT + 32 + quad * 8]);
      *(floatx4*)(av + 12) = *(const floatx4*)(&tb[m * PADT + 32 + quad * 8 + 4]);
      if (node < N) {
        union { short8 s; unsigned int u[4]; } M0, M1;
#pragma unroll
        for (int p = 0; p < 4; ++p) {
          M0.u[p] = cvtpk(av[2 * p], av[2 * p + 1]);
          M1.u[p] = cvtpk(av[8 + 2 * p], av[8 + 2 * p + 1]);
        }
        long base = (long)node * H;
        *(short8*)(Mout + base + quad * 8)      = M0.s;
        *(short8*)(Mout + base + 32 + quad * 8) = M1.s;
      }
    }
  }
}

// readout from hi/lo planes
__global__ __launch_bounds__(256) void k_out2(
    const short* __restrict__ hhi, const short* __restrict__ hlo,
    const void* __restrict__ W1, const void* __restrict__ B1,
    const void* __restrict__ W2, const void* __restrict__ B2,
    void* __restrict__ out, const int* __restrict__ flag, int NQ) {
  __shared__ float w1s[64 * 32];
  __shared__ float b1sh[32], w2s[32];
  bool isf32 = (*flag != 0);
  int tid = threadIdx.x;
  for (int idx = tid; idx < 2048; idx += 256) w1s[idx] = ldf(W1, idx, isf32);
  if (tid < 32) { b1sh[tid] = ldf(B1, tid, isf32); w2s[tid] = ldf(W2, tid, isf32); }
  __syncthreads();
  int v = blockIdx.x * 256 + tid;
  if (v >= NQ) return;
  float hr[64];
#pragma unroll
  for (int j = 0; j < 64; ++j)
    hr[j] = bf2f(hhi[(long)v * H + j]) + bf2f(hlo[(long)v * H + j]);
  float accum = ldf(B2, 0, isf32);
#pragma unroll 4
  for (int k = 0; k < 32; ++k) {
    float t = b1sh[k];
#pragma unroll
    for (int j = 0; j < 64; ++j) t += hr[j] * w1s[j * 32 + k];
    accum += fmaxf(t, 0.f) * w2s[k];
  }
  if (isf32) ((float*)out)[v] = accum;
  else ((short*)out)[v] = f2bf1(accum);
}

extern "C" void kernel_launch(void* const* d_in, const int* in_sizes, int n_in,
                              void* d_out, int out_size, void* d_ws, size_t ws_size,
                              hipStream_t stream) {
  const void* x      = d_in[0];
  const int*  ei     = (const int*)d_in[1];
  const void* w_in   = d_in[3];
  const void* b_in   = d_in[4];
  const void* msg_w1 = d_in[5];
  const void* msg_b1 = d_in[6];
  const void* msg_w2 = d_in[7];
  const void* msg_b2 = d_in[8];
  const void* upd_w1 = d_in[9];
  const void* upd_b1 = d_in[10];
  const void* upd_w2 = d_in[11];
  const void* upd_b2 = d_in[12];
  const void* bn_g   = d_in[13];
  const void* bn_b   = d_in[14];
  const void* bn_m   = d_in[15];
  const void* bn_v   = d_in[16];
  const void* out_w1 = d_in[17];
  const void* out_b1 = d_in[18];
  const void* out_w2 = d_in[19];
  const void* out_b2 = d_in[20];

  const int N = in_sizes[0] / 3;
  const int E = in_sizes[1] / 2;
  const int L = in_sizes[5] / (H * H);
  const int* srcI = ei;
  const int* dstI = ei + E;
  const int B = (N + 255) >> 8;

  // workspace layout (256B-aligned slots)
  size_t off = 0;
  auto alloc = [&](size_t bytes) { size_t o = off; off += (bytes + 255) & ~(size_t)255; return o; };
  size_t mSize = (size_t)N * H * sizeof(short);
  size_t pSize = (size_t)E * sizeof(int);   // packed 4B pairs
  size_t o_flag   = alloc(256);
  size_t o_bcnt   = alloc(1024 * sizeof(int));
  size_t o_bbase  = alloc(1025 * sizeof(int));
  size_t o_bcur   = alloc(1024 * sizeof(int));
  size_t o_prep   = alloc((size_t)L * WSTRIDE * sizeof(short));
  size_t o_hhi    = alloc((size_t)N * H * sizeof(short));
  size_t o_hlo    = alloc((size_t)N * H * sizeof(short));
  size_t o_agg    = alloc((size_t)N * H * sizeof(short));
  size_t o_M      = alloc(mSize > pSize ? mSize : pSize);  // M overlays pairs
  size_t o_rowptr = alloc((size_t)(N + 1) * sizeof(int));
  size_t o_srcS   = alloc((size_t)E * sizeof(int));

  char* ws = (char*)d_ws;
  int*   flag   = (int*)(ws + o_flag);
  int*   bcnt   = (int*)(ws + o_bcnt);
  int*   bbase  = (int*)(ws + o_bbase);
  int*   bcur   = (int*)(ws + o_bcur);
  short* prep   = (short*)(ws + o_prep);
  short* hhi    = (short*)(ws + o_hhi);
  short* hlo    = (short*)(ws + o_hlo);
  short* aggS   = (short*)(ws + o_agg);
  short* Mbuf   = (short*)(ws + o_M);
  int*   pairs  = (int*)(ws + o_M);
  int*   rowptr = (int*)(ws + o_rowptr);
  int*   srcS   = (int*)(ws + o_srcS);

  k_probe<<<1, 256, 0, stream>>>((const short*)x, flag);
  k_prep<<<L, 256, 0, stream>>>(upd_w1, upd_w2, msg_w1, msg_w2, prep, flag);
  k_input2<<<(N * H + 255) / 256, 256, 0, stream>>>(x, w_in, b_in, hhi, hlo, flag, N);

  // dense-write CSR build (packed 4B pairs)
  hipMemsetAsync(bcnt, 0, 1024 * sizeof(int), stream);
  k_bcount<<<256, 256, 0, stream>>>(dstI, bcnt, E);
  k_bscan<<<1, 256, 0, stream>>>(bcnt, bbase, bcur);
  k_bin<<<256, 256, 0, stream>>>(srcI, dstI, bcur, pairs, E);
  k_sortb<<<B, 256, 0, stream>>>(pairs, bbase, rowptr, srcS, N, E, B);

  // M_0 (full-precision standalone MLP, persistent) — after pairs is dead
  k_mlp<<<768, 256, 0, stream>>>(hhi, hlo,
      msg_w1, msg_b1, msg_w2, 0, 0, Mbuf, flag, N);

  const int nTask = (N + 7) >> 3;
  const int GB = (nTask + 7) / 8;   // 2 tasks per wave, balanced
  const int UB = (N + 255) / 256;   // 391: all co-resident, exactly 2 tiles/wave
  for (int i = 0; i < L; ++i) {
    long oB = (long)i * H;
    int doMsg = (i + 1 < L) ? 1 : 0;
    int iN = doMsg ? i + 1 : i;  // clamped (m1/m2 unused when !doMsg)
    long oBn = doMsg ? (long)(i + 1) * H : 0;
    k_gather<<<GB, 256, 0, stream>>>(Mbuf, rowptr, srcS,
        msg_b2, oB, aggS, flag, N, GB * 4);
    k_updm<<<UB, 512, 0, stream>>>(hhi, hlo, aggS,
        prep + (size_t)i * WSTRIDE, prep + (size_t)iN * WSTRIDE,
        upd_b1, upd_b2, bn_g, bn_b, bn_m, bn_v, msg_b1,
        oB, oBn, Mbuf, flag, N, doMsg);
  }
  k_out2<<<(out_size + 255) / 256, 256, 0, stream>>>(hhi, hlo,
      out_w1, out_b1, out_w2, out_b2, d_out, flag, out_size);
}